// Round 1
// baseline (33.722 us; speedup 1.0000x reference)
//
#include <hip/hip_runtime.h>
#include <hip/hip_bf16.h>

#define N_FEATURES 784
#define F4_PER_ROW (N_FEATURES / 4)   // 196
#define WAVES_PER_BLOCK 4
#define BLOCK_THREADS (WAVES_PER_BLOCK * 64)

__global__ __launch_bounds__(BLOCK_THREADS) void matvec_bias_kernel(
    const float* __restrict__ x, const float* __restrict__ w,
    const float* __restrict__ b, float* __restrict__ out, int n_rows) {
    const int wave = threadIdx.x >> 6;
    const int lane = threadIdx.x & 63;
    const int row  = blockIdx.x * WAVES_PER_BLOCK + wave;
    if (row >= n_rows) return;

    const float4* __restrict__ xr =
        reinterpret_cast<const float4*>(x + (size_t)row * N_FEATURES);
    const float4* __restrict__ wv = reinterpret_cast<const float4*>(w);

    float acc = 0.0f;
    // 196 float4 per row: 3 full wave passes (192) + tail of 4 on lanes 0..3
    #pragma unroll
    for (int k = 0; k < 3; ++k) {
        const int idx = lane + k * 64;
        float4 xv = xr[idx];
        float4 ww = wv[idx];
        acc += xv.x * ww.x + xv.y * ww.y + xv.z * ww.z + xv.w * ww.w;
    }
    if (lane < (F4_PER_ROW - 192)) {
        float4 xv = xr[192 + lane];
        float4 ww = wv[192 + lane];
        acc += xv.x * ww.x + xv.y * ww.y + xv.z * ww.z + xv.w * ww.w;
    }

    // 64-lane butterfly reduce
    #pragma unroll
    for (int off = 32; off > 0; off >>= 1)
        acc += __shfl_xor(acc, off, 64);

    if (lane == 0) out[row] = acc + b[0];
}

extern "C" void kernel_launch(void* const* d_in, const int* in_sizes, int n_in,
                              void* d_out, int out_size, void* d_ws, size_t ws_size,
                              hipStream_t stream) {
    const float* x = (const float*)d_in[0];
    const float* w = (const float*)d_in[1];
    const float* b = (const float*)d_in[2];
    float* out = (float*)d_out;

    const int n_rows = out_size;  // 65536
    const int grid = (n_rows + WAVES_PER_BLOCK - 1) / WAVES_PER_BLOCK;
    matvec_bias_kernel<<<grid, BLOCK_THREADS, 0, stream>>>(x, w, b, out, n_rows);
}